// Round 3
// baseline (280.377 us; speedup 1.0000x reference)
//
#include <hip/hip_runtime.h>
#include <stdint.h>

// ---------------------------------------------------------------------------
// EmbraceNet fused: out[b,e] = relu(x_f @ W_f + b_f)[b,e],  f = idx[b,e]
// idx = categorical(key=42): partitionable threefry, bits = y0^y1 of
// threefry2x32((0,42), (0, (e*4096+b)*4+f)); argmax over bits>>9, strict >.
// PASS since R4 (absmax 0.031).
//
// R13 == R12 resubmitted (R12 bench was an infra failure: "container failed
// twice", no kernel verdict; OOB/deadlock/race audit clean).
// R12: R11 post-mortem -- 1 block/CU killed cross-block overlap (m114);
// coarse phase hurt (m196). This round: R10's proven 128x128 / 4-wave /
// 2-blocks-per-CU geometry, but with the counted-vmcnt pipeline at BK=32:
// quad-buffered LDS (4 x 16 KiB = 64 KiB -> 2 blocks/CU), depth-3
// prefetch, per 32-K step: stage(j+3) -> 8 ds_read_b128 -> 16 MFMA ->
// s_waitcnt vmcnt(8) + raw s_barrier (stage j+1 gets ~2 steps to land;
// loads stay in flight ACROSS barriers; vmcnt(0) only in the 2-step tail).
// Bank swizzle re-derived for 64-B rows: slot = fq ^ ((row>>1)&3) -> every
// bank covered exactly 2x per b128 read (2-way = free, m136). Staged with
// pre-swizzled GLOBAL source, linear LDS dst (m173/m201 pattern).
// Bijective XCD swizzle for 512 blocks (8 x 64 exact).
// ---------------------------------------------------------------------------

typedef short short8 __attribute__((ext_vector_type(8)));
typedef float floatx4 __attribute__((ext_vector_type(4)));

#define B_DIM 4096
#define K_DIM 1024
#define E_DIM 2048

__device__ __forceinline__ uint32_t rotl32(uint32_t x, uint32_t r) {
  return __builtin_amdgcn_alignbit(x, x, 32u - r);
}

__device__ __forceinline__ uint16_t f2bf(float x) {
  uint32_t u = __float_as_uint(x);
  u += 0x7FFFu + ((u >> 16) & 1u);
  return (uint16_t)(u >> 16);
}

// JAX threefry2x32, key = (0, 42)
__device__ __forceinline__ void threefry(uint32_t x0, uint32_t x1,
                                         uint32_t& o0, uint32_t& o1) {
  const uint32_t ks0 = 0u;
  const uint32_t ks1 = 42u;
  const uint32_t ks2 = 0x1BD11BDAu ^ 42u;
  x0 += ks0; x1 += ks1;
#define TF_R(r) { x0 += x1; x1 = rotl32(x1, r); x1 ^= x0; }
  TF_R(13) TF_R(15) TF_R(26) TF_R(6)
  x0 += ks1; x1 += ks2 + 1u;
  TF_R(17) TF_R(29) TF_R(16) TF_R(24)
  x0 += ks2; x1 += ks0 + 2u;
  TF_R(13) TF_R(15) TF_R(26) TF_R(6)
  x0 += ks0; x1 += ks1 + 3u;
  TF_R(17) TF_R(29) TF_R(16) TF_R(24)
  x0 += ks1; x1 += ks2 + 4u;
  TF_R(13) TF_R(15) TF_R(26) TF_R(6)
  x0 += ks2; x1 += ks0 + 5u;
#undef TF_R
  o0 = x0; o1 = x1;
}

// 8192 blocks x 256 threads. Every thread: issue x loads (8 floats) + W
// loads (4 floats), crunch 4 idx outputs (16 threefry) while loads fly,
// then store x bf16 (16B), idx byte, and W transposed tile via LDS.
__global__ __launch_bounds__(256) void prep_kernel(
    const float* __restrict__ x0, const float* __restrict__ x1,
    const float* __restrict__ x2, const float* __restrict__ x3,
    const float* __restrict__ W0, const float* __restrict__ W1,
    const float* __restrict__ W2, const float* __restrict__ W3,
    uint16_t* __restrict__ xb, uint16_t* __restrict__ Wt,
    uint8_t* __restrict__ idx1) {
  __shared__ float tile[32][33];
  const uint32_t g = blockIdx.x;       // 0..8191
  const int t = threadIdx.x;
  const int f = g >> 11;               // plane 0..3
  const uint32_t ip = g & 2047u;       // tile/chunk within plane

  // ---- issue x loads: plane f, 8 consecutive floats per thread ----
  const float* x = (f == 0) ? x0 : (f == 1) ? x1 : (f == 2) ? x2 : x3;
  const size_t xoff = ((size_t)ip * 256 + t) * 8;
  float4 v0 = *(const float4*)(x + xoff);
  float4 v1 = *(const float4*)(x + xoff + 4);

  // ---- issue W loads: 32x32 tile ip of plane f ----
  const float* W = (f == 0) ? W0 : (f == 1) ? W1 : (f == 2) ? W2 : W3;
  const int e0 = (int)(ip & 63) * 32, k0 = (int)(ip >> 6) * 32;
  const int tx = t & 31, ty = t >> 5;
  float wv[4];
#pragma unroll
  for (int i = 0; i < 4; ++i)
    wv[i] = W[(size_t)(k0 + ty + i * 8) * E_DIM + e0 + tx];

  // ---- threefry crunch: outputs o0..o0+3, pack 2 bits each ----
  const uint32_t o0i = (g * 256u + t) * 4u;
  uint32_t byte = 0;
#pragma unroll
  for (uint32_t q = 0; q < 4; ++q) {
    uint32_t c = (o0i + q) << 2;
    uint32_t best = 0, bi = 0;
#pragma unroll
    for (uint32_t ff = 0; ff < 4; ++ff) {
      uint32_t y0, y1;
      threefry(0u, c + ff, y0, y1);
      uint32_t m = (y0 ^ y1) >> 9;
      if (ff == 0) best = m;
      else if (m > best) { best = m; bi = ff; }
    }
    byte |= bi << (2 * q);
  }
  idx1[g * 256u + t] = (uint8_t)byte;

  // ---- x store: 8 bf16 = 16B ----
  {
    union { uint16_t h[8]; uint64_t q[2]; } p;
    p.h[0] = f2bf(v0.x); p.h[1] = f2bf(v0.y);
    p.h[2] = f2bf(v0.z); p.h[3] = f2bf(v0.w);
    p.h[4] = f2bf(v1.x); p.h[5] = f2bf(v1.y);
    p.h[6] = f2bf(v1.z); p.h[7] = f2bf(v1.w);
    uint64_t* dst = (uint64_t*)(xb + (size_t)f * B_DIM * K_DIM + xoff);
    dst[0] = p.q[0]; dst[1] = p.q[1];
  }

  // ---- W transpose via LDS ----
#pragma unroll
  for (int i = 0; i < 4; ++i) tile[ty + i * 8][tx] = wv[i];
  __syncthreads();
  {
    const int el = t >> 3, kc = (t & 7) * 4;
    union { uint16_t h[4]; uint64_t q; } p;
#pragma unroll
    for (int i = 0; i < 4; ++i) p.h[i] = f2bf(tile[kc + i][el]);
    uint16_t* dst = Wt + (size_t)f * E_DIM * K_DIM;
    *(uint64_t*)(dst + (size_t)(e0 + el) * K_DIM + k0 + kc) = p.q;
  }
}

__device__ __forceinline__ void async16(const uint16_t* g, uint16_t* lds) {
  __builtin_amdgcn_global_load_lds(
      (const __attribute__((address_space(1))) void*)g,
      (__attribute__((address_space(3))) void*)lds, 16, 0, 0);
}

#define PLANE_A ((size_t)B_DIM * K_DIM)
#define PLANE_B ((size_t)E_DIM * K_DIM)
#define BK 32

// 256 threads (4 waves, 2x2 of 64x64), 128x128 tile, BK=32, flat 128-step
// loop (f = j>>5), quad-buffered LDS (64 KiB -> 2 blocks/CU), depth-3
// prefetch, counted vmcnt(8) per step. LDS row = 32 bf16 (64 B), slot p of
// row r holds global k-chunk p ^ ((r>>1)&3)  (2-way bank coverage = free).
__global__ __launch_bounds__(256, 2) void gemm_fused(
    const uint16_t* __restrict__ Ab, const uint16_t* __restrict__ Bbt,
    const uint32_t* __restrict__ idx2,
    const float* __restrict__ bias0, const float* __restrict__ bias1,
    const float* __restrict__ bias2, const float* __restrict__ bias3,
    float* __restrict__ out) {
  __shared__ uint16_t As[4][128 * BK];   // 4 x 8 KiB
  __shared__ uint16_t Bs[4][128 * BK];   // 4 x 8 KiB

  const int tid = threadIdx.x;
  const int w = tid >> 6;        // 0..3
  const int l = tid & 63;

  // bijective XCD-chunked swizzle: 512 blocks = 8 XCDs x 64 contiguous
  const int flat = (int)(blockIdx.y * gridDim.x + blockIdx.x);
  const int swz = (flat & 7) * 64 + (flat >> 3);
  const int mBase = (swz >> 4) * 128;    // 32 M-tiles
  const int nBase = (swz & 15) * 128;    // 16 N-tiles

  const int wm = (w >> 1) * 64, wn = (w & 1) * 64;
  const int fr = l & 15, fq = l >> 4;

  // staging: wave w stages rows 32w..32w+31 of A and B, 2 instrs each.
  // lane l -> row sRow = l>>2 (within 16-row group), slot p = l&3;
  // global chunk for (row, slot p) = p ^ ((row>>1)&3)  (tt-invariant).
  const int sRow = l >> 2;
  const int gck = ((l & 3) ^ ((sRow >> 1) & 3)) * 8;
  const uint16_t* aS = Ab + (size_t)(mBase + 32 * w + sRow) * K_DIM + gck;
  const uint16_t* bS = Bbt + (size_t)(nBase + 32 * w + sRow) * K_DIM + gck;

  // read-side: slot for global chunk fq of row (row%16 == fr):
  const int kread = ((fq ^ ((fr >> 1) & 3))) * 8;

  // preload selection words + bias into regs (keeps the in-loop vmcnt
  // stream pure staging loads)
  const int b_hi0 = (mBase + wm) >> 4;
  uint32_t iw[4][4];
#pragma unroll
  for (int ni = 0; ni < 4; ++ni) {
    int col = nBase + wn + ni * 16 + fr;
#pragma unroll
    for (int mi = 0; mi < 4; ++mi)
      iw[ni][mi] = idx2[(size_t)col * (B_DIM / 16) + b_hi0 + mi];
  }
  float bz0[4], bz1[4], bz2[4], bz3[4];
#pragma unroll
  for (int ni = 0; ni < 4; ++ni) {
    int col = nBase + wn + ni * 16 + fr;
    bz0[ni] = bias0[col]; bz1[ni] = bias1[col];
    bz2[ni] = bias2[col]; bz3[ni] = bias3[col];
  }

  // stage 32-K step t into buffer tb: 2 A-instrs + 2 B-instrs per wave
  auto stage = [&](int t, int tb) {
    const int fA = t >> 5, ko = (t & 31) * BK;
    const uint16_t* pA = aS + (size_t)fA * PLANE_A + ko;
    const uint16_t* pB = bS + (size_t)fA * PLANE_B + ko;
    async16(pA, &As[tb][(2 * w + 0) * 512]);
    async16(pA + (size_t)16 * K_DIM, &As[tb][(2 * w + 1) * 512]);
    async16(pB, &Bs[tb][(2 * w + 0) * 512]);
    async16(pB + (size_t)16 * K_DIM, &Bs[tb][(2 * w + 1) * 512]);
  };

  floatx4 acc[4][4] = {};
  floatx4 res[4][4] = {};

  // prologue: fill buffers 0..2; vmcnt(8) leaves the 8 newest (stages 1,2)
  // in flight, drains iw/bias + stage 0.
  stage(0, 0);
  stage(1, 1);
  stage(2, 2);
  asm volatile("s_waitcnt vmcnt(8)" ::: "memory");
  __builtin_amdgcn_s_barrier();
  asm volatile("" ::: "memory");

#pragma unroll 1
  for (int j = 0; j < 128; ++j) {
    if (j + 3 < 128) stage(j + 3, (j + 3) & 3);

    const uint16_t* cA = &As[j & 3][0];
    const uint16_t* cB = &Bs[j & 3][0];
    short8 a[4], b[4];
#pragma unroll
    for (int mi = 0; mi < 4; ++mi)
      a[mi] = *(const short8*)&cA[(wm + mi * 16 + fr) * BK + kread];
#pragma unroll
    for (int ni = 0; ni < 4; ++ni)
      b[ni] = *(const short8*)&cB[(wn + ni * 16 + fr) * BK + kread];
    __builtin_amdgcn_s_setprio(1);
#pragma unroll
    for (int mi = 0; mi < 4; ++mi)
#pragma unroll
      for (int ni = 0; ni < 4; ++ni)
        acc[mi][ni] = __builtin_amdgcn_mfma_f32_16x16x32_bf16(
            a[mi], b[ni], acc[mi][ni], 0, 0, 0);
    __builtin_amdgcn_s_setprio(0);

    // f-boundary: fold this plane's acc into res where selected, reset acc
    if ((j & 31) == 31) {
      const int f = j >> 5;
#pragma unroll
      for (int ni = 0; ni < 4; ++ni) {
        float bv = (f == 0) ? bz0[ni] : (f == 1) ? bz1[ni]
                 : (f == 2) ? bz2[ni] : bz3[ni];
#pragma unroll
        for (int mi = 0; mi < 4; ++mi) {
          uint32_t wd = iw[ni][mi];
#pragma unroll
          for (int r = 0; r < 4; ++r) {
            uint32_t sel = (wd >> (2 * (fq * 4 + r))) & 3u;
            if (sel == (uint32_t)f) res[mi][ni][r] = acc[mi][ni][r] + bv;
            acc[mi][ni][r] = 0.f;
          }
        }
      }
    }

    // counted wait: drain everything older than stages j+2,j+3  ==>
    // stage(j+1) (next step's buffer) has landed. Tail drains 4 -> 0.
    if (j < 125) {
      asm volatile("s_waitcnt vmcnt(8)" ::: "memory");
      __builtin_amdgcn_s_barrier();
      asm volatile("" ::: "memory");
    } else if (j == 125) {
      asm volatile("s_waitcnt vmcnt(4)" ::: "memory");
      __builtin_amdgcn_s_barrier();
      asm volatile("" ::: "memory");
    } else if (j == 126) {
      asm volatile("s_waitcnt vmcnt(0)" ::: "memory");
      __builtin_amdgcn_s_barrier();
      asm volatile("" ::: "memory");
    }
  }

  // dense coalesced store with relu. C/D: col=lane&15, row=(lane>>4)*4+reg
#pragma unroll
  for (int ni = 0; ni < 4; ++ni) {
    int col = nBase + wn + ni * 16 + fr;
#pragma unroll
    for (int mi = 0; mi < 4; ++mi) {
      int row0 = mBase + wm + mi * 16 + fq * 4;
#pragma unroll
      for (int r = 0; r < 4; ++r) {
        float o = res[mi][ni][r];
        __builtin_nontemporal_store(o > 0.f ? o : 0.f,
                                    &out[(size_t)(row0 + r) * E_DIM + col]);
      }
    }
  }
}

extern "C" void kernel_launch(void* const* d_in, const int* in_sizes, int n_in,
                              void* d_out, int out_size, void* d_ws, size_t ws_size,
                              hipStream_t stream) {
  const float* x[4]; const float* W[4]; const float* bs[4];
  for (int f = 0; f < 4; ++f) {
    x[f]  = (const float*)d_in[3 * f + 0];
    W[f]  = (const float*)d_in[3 * f + 1];
    bs[f] = (const float*)d_in[3 * f + 2];
  }
  char* ws = (char*)d_ws;
  uint16_t* xb  = (uint16_t*)ws;                               // 32 MB
  uint16_t* Wt  = (uint16_t*)(ws + (size_t)32 * 1024 * 1024);  // 16 MB
  uint8_t*  idx1 = (uint8_t*)(ws + (size_t)48 * 1024 * 1024);  //  2 MB
  float* out = (float*)d_out;

  prep_kernel<<<dim3(8192), dim3(256), 0, stream>>>(
      x[0], x[1], x[2], x[3], W[0], W[1], W[2], W[3], xb, Wt, idx1);
  gemm_fused<<<dim3(E_DIM / 128, B_DIM / 128), dim3(256), 0, stream>>>(
      xb, Wt, (const uint32_t*)idx1, bs[0], bs[1], bs[2], bs[3], out);
}